// Round 4
// baseline (433.555 us; speedup 1.0000x reference)
//
#include <hip/hip_runtime.h>

// Binarize: x[2048,32768] f32, 3 thresholds -> packed bits (big-endian per byte)
// emitted as int32 values 0..255, shape [2048, 3, 4096].
// Memory-bound: 268 MB read + 101 MB write => ~59 us floor at 6.3 TB/s.
//
// Each thread: 4 consecutive byte-groups (32 floats = 128 B contiguous loads),
// one 16-B nontemporal store per depth. Native ext_vector types because
// __builtin_nontemporal_* rejects HIP_vector_type structs.

constexpr int B_ROWS = 2048;
constexpr int N_COLS = 32768;
constexpr int NB = N_COLS / 8;       // 4096 packed bytes per row per depth
constexpr int D = 3;
constexpr int GP = 4;                // byte-groups per thread
constexpr int GROUPS = NB / GP;      // 1024 thread-columns per row

typedef float vfloat4 __attribute__((ext_vector_type(4)));
typedef int   vint4   __attribute__((ext_vector_type(4)));

__device__ __forceinline__ unsigned pack8(const vfloat4& a, const vfloat4& b, float t) {
    unsigned p = 0;
    p = (p << 1) | (a.x > t ? 1u : 0u);
    p = (p << 1) | (a.y > t ? 1u : 0u);
    p = (p << 1) | (a.z > t ? 1u : 0u);
    p = (p << 1) | (a.w > t ? 1u : 0u);
    p = (p << 1) | (b.x > t ? 1u : 0u);
    p = (p << 1) | (b.y > t ? 1u : 0u);
    p = (p << 1) | (b.z > t ? 1u : 0u);
    p = (p << 1) | (b.w > t ? 1u : 0u);
    return p;
}

__global__ __launch_bounds__(256) void Binarize_52913997086767_kernel(
    const float* __restrict__ x,
    const float* __restrict__ ths,
    int* __restrict__ out)
{
    unsigned idx = blockIdx.x * 256u + threadIdx.x;   // 0 .. B_ROWS*GROUPS-1
    unsigned row = idx >> 10;                         // / 1024
    unsigned grp = (idx & 1023u) << 2;                // starting byte-group (x4)

    const vfloat4* xp = reinterpret_cast<const vfloat4*>(
        x + ((size_t)row << 15) + ((size_t)grp << 3));

    vfloat4 v[8];
#pragma unroll
    for (int i = 0; i < 8; ++i)
        v[i] = __builtin_nontemporal_load(&xp[i]);

    float t0 = ths[0];
    float t1 = ths[1];
    float t2 = ths[2];

    vint4 w0, w1, w2;
    w0.x = (int)pack8(v[0], v[1], t0);
    w0.y = (int)pack8(v[2], v[3], t0);
    w0.z = (int)pack8(v[4], v[5], t0);
    w0.w = (int)pack8(v[6], v[7], t0);

    w1.x = (int)pack8(v[0], v[1], t1);
    w1.y = (int)pack8(v[2], v[3], t1);
    w1.z = (int)pack8(v[4], v[5], t1);
    w1.w = (int)pack8(v[6], v[7], t1);

    w2.x = (int)pack8(v[0], v[1], t2);
    w2.y = (int)pack8(v[2], v[3], t2);
    w2.z = (int)pack8(v[4], v[5], t2);
    w2.w = (int)pack8(v[6], v[7], t2);

    int* obase = out + (size_t)row * (D * NB) + grp;
    __builtin_nontemporal_store(w0, reinterpret_cast<vint4*>(obase));
    __builtin_nontemporal_store(w1, reinterpret_cast<vint4*>(obase + NB));
    __builtin_nontemporal_store(w2, reinterpret_cast<vint4*>(obase + 2 * NB));
}

extern "C" void kernel_launch(void* const* d_in, const int* in_sizes, int n_in,
                              void* d_out, int out_size, void* d_ws, size_t ws_size,
                              hipStream_t stream) {
    const float* x   = (const float*)d_in[0];
    const float* ths = (const float*)d_in[1];
    int* out = (int*)d_out;

    const int total_threads = B_ROWS * GROUPS;        // 2,097,152
    dim3 grid(total_threads / 256);                   // 8192 blocks
    dim3 block(256);
    Binarize_52913997086767_kernel<<<grid, block, 0, stream>>>(x, ths, out);
}

// Round 5
// 395.449 us; speedup vs baseline: 1.0964x; 1.0964x over previous
//
#include <hip/hip_runtime.h>

// Binarize: x[2048,32768] f32, 3 thresholds -> packed bits (big-endian per byte)
// emitted as int32 values 0..255, shape [2048, 3, 4096].
// Memory-bound: 268 MB read + 101 MB write => ~59 us floor at 6.3 TB/s.
//
// Layout lesson (R4 post-mortem): per-INSTRUCTION lane contiguity is what
// matters. Each thread owns 8 consecutive floats (one output byte per depth);
// loads are 2x dwordx4 with lanes at stride 32 B (2 lanes per 64-B line, the
// second instruction hits L1). Plain cached loads; nontemporal stores only
// (write-only stream, full lines per instruction). 4 byte-groups per thread
// via grid-stride for MLP.

constexpr int B_ROWS = 2048;
constexpr int N_COLS = 32768;
constexpr int NB = N_COLS / 8;       // 4096 packed bytes per row per depth
constexpr int D = 3;
constexpr int ITERS = 4;
constexpr int BLOCKS = (B_ROWS * NB) / (256 * ITERS);   // 8192
constexpr unsigned STRIDE = BLOCKS * 256u;              // groups per iteration step

typedef float vfloat4 __attribute__((ext_vector_type(4)));

__device__ __forceinline__ unsigned pack8(const vfloat4& a, const vfloat4& b, float t) {
    unsigned p = 0;
    p = (p << 1) | (a.x > t ? 1u : 0u);
    p = (p << 1) | (a.y > t ? 1u : 0u);
    p = (p << 1) | (a.z > t ? 1u : 0u);
    p = (p << 1) | (a.w > t ? 1u : 0u);
    p = (p << 1) | (b.x > t ? 1u : 0u);
    p = (p << 1) | (b.y > t ? 1u : 0u);
    p = (p << 1) | (b.z > t ? 1u : 0u);
    p = (p << 1) | (b.w > t ? 1u : 0u);
    return p;
}

__global__ __launch_bounds__(256) void Binarize_52913997086767_kernel(
    const float* __restrict__ x,
    const float* __restrict__ ths,
    int* __restrict__ out)
{
    unsigned tid0 = blockIdx.x * 256u + threadIdx.x;

    float t0 = ths[0];
    float t1 = ths[1];
    float t2 = ths[2];

    // Load all iterations' data first: 8 independent dwordx4 in flight.
    vfloat4 a[ITERS], b[ITERS];
#pragma unroll
    for (int i = 0; i < ITERS; ++i) {
        unsigned idx  = tid0 + (unsigned)i * STRIDE;
        unsigned row  = idx >> 12;          // / 4096
        unsigned grp  = idx & 4095u;        // % 4096
        const vfloat4* xp = reinterpret_cast<const vfloat4*>(
            x + ((size_t)row << 15) + ((size_t)grp << 3));
        a[i] = xp[0];
        b[i] = xp[1];
    }

#pragma unroll
    for (int i = 0; i < ITERS; ++i) {
        unsigned idx  = tid0 + (unsigned)i * STRIDE;
        unsigned row  = idx >> 12;
        unsigned grp  = idx & 4095u;

        unsigned p0 = pack8(a[i], b[i], t0);
        unsigned p1 = pack8(a[i], b[i], t1);
        unsigned p2 = pack8(a[i], b[i], t2);

        int* o = out + (size_t)row * (D * NB) + grp;
        __builtin_nontemporal_store((int)p0, o);
        __builtin_nontemporal_store((int)p1, o + NB);
        __builtin_nontemporal_store((int)p2, o + 2 * NB);
    }
}

extern "C" void kernel_launch(void* const* d_in, const int* in_sizes, int n_in,
                              void* d_out, int out_size, void* d_ws, size_t ws_size,
                              hipStream_t stream) {
    const float* x   = (const float*)d_in[0];
    const float* ths = (const float*)d_in[1];
    int* out = (int*)d_out;

    dim3 grid(BLOCKS);
    dim3 block(256);
    Binarize_52913997086767_kernel<<<grid, block, 0, stream>>>(x, ths, out);
}